// Round 4
// baseline (164.831 us; speedup 1.0000x reference)
//
#include <hip/hip_runtime.h>
#include <hip/hip_bf16.h>

// B=2, H=16, S=2048, D=64, DMODEL=1024
// Round 4: occupancy was GRID-limited (512 blocks = 2/CU). attn -> 512-thread
// blocks (8 waves = 16 waves/CU), wave = (32-q group, 32-kv half), end-of-loop
// LDS pair-reduction of partial O/L. proj -> M64xN64 quadrant tiles, grid
// (64,16)=1024 blocks = 4/CU.

typedef float  f32x16 __attribute__((ext_vector_type(16)));
typedef float  f32x4v __attribute__((ext_vector_type(4)));
typedef float  f32x2v __attribute__((ext_vector_type(2)));
typedef __bf16 bf16x8 __attribute__((ext_vector_type(8)));
typedef __bf16 bf16x4 __attribute__((ext_vector_type(4)));
typedef __bf16 bf16x2 __attribute__((ext_vector_type(2)));

static constexpr int Bn = 2, Hn = 16, Sn = 2048, Dn = 64, DM = 1024;
static constexpr size_t QKV_ELEMS = (size_t)Bn * Hn * Sn * Dn;   // 4,194,304

#define QSCALE 0.18033688011112042f   // 0.125 * log2(e)

#if __has_builtin(__builtin_amdgcn_cvt_pk_bf16_f32)
static __device__ __forceinline__ unsigned pack2(float a, float b) {
  bf16x2 t = __builtin_amdgcn_cvt_pk_bf16_f32(a, b);
  union { bf16x2 v; unsigned u; } c; c.v = t; return c.u;
}
#else
static __device__ __forceinline__ unsigned pack2(float a, float b) {
  union { __bf16 h; unsigned short s; } ua, ub;
  ua.h = (__bf16)a; ub.h = (__bf16)b;
  return (unsigned)ua.s | ((unsigned)ub.s << 16);
}
#endif

static __device__ __forceinline__ void unzip8(const unsigned* wds, bf16x8* r0, bf16x8* r1) {
  union { unsigned u[4]; bf16x8 v; } a, b;
#pragma unroll
  for (int i = 0; i < 4; ++i) {
    unsigned lo = wds[2 * i], hi = wds[2 * i + 1];
    a.u[i] = (lo & 0xffffu) | (hi << 16);
    b.u[i] = (lo >> 16) | (hi & 0xffff0000u);
  }
  *r0 = a.v; *r1 = b.v;
}

// ---------------------------------------------------------------- converts
__global__ __launch_bounds__(256) void convert_qk(
    const float* __restrict__ q, const float* __restrict__ k,
    __bf16* __restrict__ qo, __bf16* __restrict__ ko) {
  const int z = blockIdx.y;
  const float* src = z ? k : q;
  __bf16* dst      = z ? ko : qo;
  const float scale = z ? 1.0f : QSCALE;
  size_t i = ((size_t)blockIdx.x * 256 + threadIdx.x) * 8;
  f32x4v a = *(const f32x4v*)(src + i);
  f32x4v b = *(const f32x4v*)(src + i + 4);
  bf16x8 o;
#pragma unroll
  for (int j = 0; j < 4; ++j) { o[j] = (__bf16)(a[j] * scale); o[4 + j] = (__bf16)(b[j] * scale); }
  *(bf16x8*)(dst + i) = o;
}

// V (b,h,kv,d) fp32 -> Vt (b,h,d,kv) bf16.
__global__ __launch_bounds__(256) void convert_vt(const float* __restrict__ v,
                                                  __bf16* __restrict__ vt) {
  __shared__ __bf16 T[64][74];
  const int t = threadIdx.x, r = t >> 2, c0 = (t & 3) * 16;
  const int kv0 = blockIdx.x * 64, bh = blockIdx.y;
  const float* src = v + ((size_t)bh * Sn + kv0 + r) * Dn + c0;
  union { bf16x8 v8; unsigned u[4]; } o0, o1;
#pragma unroll
  for (int i = 0; i < 2; ++i) {
    f32x4v f = *(const f32x4v*)(src + i * 4);
#pragma unroll
    for (int j = 0; j < 4; ++j) o0.v8[i * 4 + j] = (__bf16)f[j];
  }
#pragma unroll
  for (int i = 0; i < 2; ++i) {
    f32x4v f = *(const f32x4v*)(src + 8 + i * 4);
#pragma unroll
    for (int j = 0; j < 4; ++j) o1.v8[i * 4 + j] = (__bf16)f[j];
  }
#pragma unroll
  for (int j = 0; j < 4; ++j) {
    *(unsigned*)&T[r][c0 + 2 * j]     = o0.u[j];
    *(unsigned*)&T[r][c0 + 8 + 2 * j] = o1.u[j];
  }
  __syncthreads();
  const int rp = t >> 3, k0 = (t & 7) * 8;
  unsigned wds[8];
#pragma unroll
  for (int i = 0; i < 8; ++i) wds[i] = *(const unsigned*)&T[k0 + i][2 * rp];
  bf16x8 r0, r1; unzip8(wds, &r0, &r1);
  __bf16* dst = vt + ((size_t)bh * Dn + 2 * rp) * Sn + kv0 + k0;
  *(bf16x8*)dst = r0;
  *(bf16x8*)(dst + Sn) = r1;
}

// W (k,n) fp32 -> Wt (n,k) bf16.
__global__ __launch_bounds__(256) void convert_w(const float* __restrict__ w,
                                                 __bf16* __restrict__ wt) {
  __shared__ __bf16 T[64][74];
  const int t = threadIdx.x, r = t >> 2, c0 = (t & 3) * 16;
  const int nt = blockIdx.x * 64, kt = blockIdx.y * 64;
  const float* src = w + (size_t)(kt + r) * DM + nt + c0;
  union { bf16x8 v8; unsigned u[4]; } o0, o1;
#pragma unroll
  for (int i = 0; i < 2; ++i) {
    f32x4v f = *(const f32x4v*)(src + i * 4);
#pragma unroll
    for (int j = 0; j < 4; ++j) o0.v8[i * 4 + j] = (__bf16)f[j];
  }
#pragma unroll
  for (int i = 0; i < 2; ++i) {
    f32x4v f = *(const f32x4v*)(src + 8 + i * 4);
#pragma unroll
    for (int j = 0; j < 4; ++j) o1.v8[i * 4 + j] = (__bf16)f[j];
  }
#pragma unroll
  for (int j = 0; j < 4; ++j) {
    *(unsigned*)&T[r][c0 + 2 * j]     = o0.u[j];
    *(unsigned*)&T[r][c0 + 8 + 2 * j] = o1.u[j];
  }
  __syncthreads();
  const int rp = t >> 3, k0 = (t & 7) * 8;
  unsigned wds[8];
#pragma unroll
  for (int i = 0; i < 8; ++i) wds[i] = *(const unsigned*)&T[k0 + i][2 * rp];
  bf16x8 r0, r1; unzip8(wds, &r0, &r1);
  __bf16* dst = wt + (size_t)(nt + 2 * rp) * DM + kt + k0;
  *(bf16x8*)dst = r0;
  *(bf16x8*)(dst + DM) = r1;
}

// ---------------------------------------------------------------- attention
// grid (S/128, H, B), 512 threads = 8 waves. wave = (qg = wave>>1 owning 32 q
// rows, kh = wave&1 owning a 32-kv half of each 64-kv tile). Partial O/L
// pair-reduced via LDS after the loop. 2 blocks/CU x 8 waves = 16 waves/CU.
__global__ __launch_bounds__(512, 4) void attn(
    const __bf16* __restrict__ Qb, const __bf16* __restrict__ Kb,
    const __bf16* __restrict__ Vtg, __bf16* __restrict__ Cc) {
  const int tid = threadIdx.x;
  const int wave = tid >> 6, lane = tid & 63;
  const int ln = lane & 31, g = lane >> 5;
  const int qg = wave >> 1, kh = wave & 1;
  const int qb = blockIdx.x, h = blockIdx.y, bz = blockIdx.z;

  __shared__ __bf16 smem[2][2][64][72];      // 36864 B
  __bf16 (*Ks)[64][72] = smem[0];            // [buf][kv][d]
  __bf16 (*Vs)[64][72] = smem[1];            // [buf][d][kv]

  const size_t hoff = (size_t)(bz * Hn + h) * Sn * Dn;
  const __bf16* Qp = Qb + hoff + (size_t)(qb * 128 + qg * 32) * Dn;
  const __bf16* Kp = Kb + hoff;      // [kv][d]
  const __bf16* Vp = Vtg + hoff;     // [d][kv]

  bf16x8 qf[4];
#pragma unroll
  for (int ks = 0; ks < 4; ++ks)
    qf[ks] = *(const bf16x8*)(Qp + (size_t)ln * Dn + ks * 16 + g * 8);

  // staging: 512 threads x 8 elems per tile
  const int sr = tid >> 3, sc = (tid & 7) * 8;
  const __bf16* kbase = Kp + (size_t)sr * Dn + sc;
  const __bf16* vbase = Vp + (size_t)sr * Sn + sc;

  bf16x8 k0r = *(const bf16x8*)kbase;
  bf16x8 v0r = *(const bf16x8*)vbase;
  *(bf16x8*)&Ks[0][sr][sc] = k0r;
  *(bf16x8*)&Vs[0][sr][sc] = v0r;
  k0r = *(const bf16x8*)(kbase + (size_t)64 * Dn);
  v0r = *(const bf16x8*)(vbase + 64);
  __syncthreads();

  f32x16 O0 = {}, O1 = {};
  float Lown = 0.0f;
  constexpr int NT = Sn / 64;

  for (int kt = 0; kt < NT; ++kt) {
    const int buf = kt & 1;

    // S^T 32kv x 32q tile for this wave's kv-half; p = exp2(s)
    f32x16 s = {};
#pragma unroll
    for (int ks = 0; ks < 4; ++ks) {
      bf16x8 kf = *(const bf16x8*)&Ks[buf][kh * 32 + ln][ks * 16 + g * 8];
      s = __builtin_amdgcn_mfma_f32_32x32x16_bf16(kf, qf[ks], s, 0, 0, 0);
    }
    float p[16];
#pragma unroll
    for (int r = 0; r < 16; ++r) p[r] = __builtin_amdgcn_exp2f(s[r]);
    f32x2v s2 = {0.0f, 0.0f};
#pragma unroll
    for (int tt = 0; tt < 8; ++tt) { f32x2v t2 = {p[2 * tt], p[2 * tt + 1]}; s2 += t2; }
    Lown += s2[0] + s2[1];

    unsigned w[8];
#pragma unroll
    for (int tt = 0; tt < 8; ++tt) w[tt] = pack2(p[2 * tt], p[2 * tt + 1]);

    // stage next tile into the other buffer; prefetch kt+2
    if (kt + 1 < NT) {
      const int nb = buf ^ 1;
      *(bf16x8*)&Ks[nb][sr][sc] = k0r;
      *(bf16x8*)&Vs[nb][sr][sc] = v0r;
      if (kt + 2 < NT) {
        k0r = *(const bf16x8*)(kbase + (size_t)(kt + 2) * 64 * Dn);
        v0r = *(const bf16x8*)(vbase + (kt + 2) * 64);
      }
    }

    // PV over this wave's 32 kv: 2 K-steps of 16
#pragma unroll
    for (int s4 = 0; s4 < 2; ++s4) {
      const int wb = s4 * 4;
      unsigned xs0 = g ? w[wb + 0] : w[wb + 2];
      unsigned xs1 = g ? w[wb + 1] : w[wb + 3];
      unsigned x0 = (unsigned)__shfl_xor((int)xs0, 32);
      unsigned x1 = (unsigned)__shfl_xor((int)xs1, 32);
      union { unsigned u[4]; bf16x8 v; } pu;
      pu.u[0] = g ? x0 : w[wb + 0];
      pu.u[1] = g ? x1 : w[wb + 1];
      pu.u[2] = g ? w[wb + 2] : x0;
      pu.u[3] = g ? w[wb + 3] : x1;
      bf16x8 vf0 = *(const bf16x8*)&Vs[buf][ln][kh * 32 + s4 * 16 + g * 8];
      bf16x8 vf1 = *(const bf16x8*)&Vs[buf][32 + ln][kh * 32 + s4 * 16 + g * 8];
      O0 = __builtin_amdgcn_mfma_f32_32x32x16_bf16(vf0, pu.v, O0, 0, 0, 0);
      O1 = __builtin_amdgcn_mfma_f32_32x32x16_bf16(vf1, pu.v, O1, 0, 0, 0);
    }
    __syncthreads();
  }

  // ---- pair reduction (kh=1 -> kh=0) via LDS, then normalize + store ----
  const float Lred = Lown + __shfl_xor(Lown, 32);
  float* Ex = (float*)smem;                  // [4*64][36] f32 = 36864 B exactly
  const int slot = (qg * 64 + lane) * 36;
  if (kh == 1) {
#pragma unroll
    for (int i = 0; i < 4; ++i) {
      f32x4v t = {O0[4 * i], O0[4 * i + 1], O0[4 * i + 2], O0[4 * i + 3]};
      *(f32x4v*)&Ex[slot + 4 * i] = t;
    }
#pragma unroll
    for (int i = 0; i < 4; ++i) {
      f32x4v t = {O1[4 * i], O1[4 * i + 1], O1[4 * i + 2], O1[4 * i + 3]};
      *(f32x4v*)&Ex[slot + 16 + 4 * i] = t;
    }
    Ex[slot + 32] = Lred;
  }
  __syncthreads();
  float inv = 0.0f;
  if (kh == 0) {
#pragma unroll
    for (int i = 0; i < 4; ++i) {
      f32x4v t = *(const f32x4v*)&Ex[slot + 4 * i];
#pragma unroll
      for (int c = 0; c < 4; ++c) O0[4 * i + c] += t[c];
    }
#pragma unroll
    for (int i = 0; i < 4; ++i) {
      f32x4v t = *(const f32x4v*)&Ex[slot + 16 + 4 * i];
#pragma unroll
      for (int c = 0; c < 4; ++c) O1[4 * i + c] += t[c];
    }
    inv = 1.0f / (Lred + Ex[slot + 32]);
  }
  __syncthreads();                           // all exchange reads complete
  __bf16* T = (__bf16*)smem;                 // [128][72] bf16 = 18432 B
  if (kh == 0) {
#pragma unroll
    for (int dh = 0; dh < 2; ++dh) {
#pragma unroll
      for (int a = 0; a < 4; ++a) {
        const f32x16 O = dh ? O1 : O0;
        bf16x4 t4;
#pragma unroll
        for (int c = 0; c < 4; ++c) t4[c] = (__bf16)(O[4 * a + c] * inv);
        *(bf16x4*)&T[(qg * 32 + ln) * 72 + dh * 32 + 8 * a + 4 * g] = t4;
      }
    }
  }
  __syncthreads();
  const int q0 = qb * 128;
#pragma unroll
  for (int i = 0; i < 2; ++i) {
    const int rq = wave * 16 + i * 8 + (lane >> 3);
    const int c8 = (lane & 7) * 8;
    bf16x8 o = *(const bf16x8*)&T[rq * 72 + c8];
    size_t base = (((size_t)bz * Sn + q0 + rq) * Hn + h) * Dn + c8;
    *(bf16x8*)&Cc[base] = o;
  }
}

// ---------------------------------------------------------------- projection
// out(4096,1024) = concat @ W + b. M64 x N64 tiles, 4 waves = quadrants,
// grid (64,16) = 1024 blocks = 4/CU. Double-buffered, one barrier/iter.
__global__ __launch_bounds__(256, 4) void proj(
    const __bf16* __restrict__ A, const __bf16* __restrict__ Wt,
    const float* __restrict__ bias, float* __restrict__ out) {
  const int tid = threadIdx.x, wave = tid >> 6, lane = tid & 63;
  const int ln = lane & 31, g = lane >> 5;
  const int mh = wave >> 1, nh = wave & 1;
  const int bm = blockIdx.x, bn = blockIdx.y;
  __shared__ __bf16 As[2][64][72];
  __shared__ __bf16 Bs[2][64][72];
  const int ar = tid >> 2, ac = (tid & 3) * 16;
  f32x16 acc = {};
  const __bf16* Ap = A + (size_t)(bm * 64) * DM;
  const __bf16* Wp = Wt + (size_t)(bn * 64) * DM;

  bf16x8 a0, a1, b0, b1;
  {
    const __bf16* ap = Ap + (size_t)ar * DM + ac;
    a0 = *(const bf16x8*)ap; a1 = *(const bf16x8*)(ap + 8);
    const __bf16* wp = Wp + (size_t)ar * DM + ac;
    b0 = *(const bf16x8*)wp; b1 = *(const bf16x8*)(wp + 8);
  }
  *(bf16x8*)&As[0][ar][ac]     = a0;
  *(bf16x8*)&As[0][ar][ac + 8] = a1;
  *(bf16x8*)&Bs[0][ar][ac]     = b0;
  *(bf16x8*)&Bs[0][ar][ac + 8] = b1;
  {
    const __bf16* ap = Ap + (size_t)ar * DM + 64 + ac;
    a0 = *(const bf16x8*)ap; a1 = *(const bf16x8*)(ap + 8);
    const __bf16* wp = Wp + (size_t)ar * DM + 64 + ac;
    b0 = *(const bf16x8*)wp; b1 = *(const bf16x8*)(wp + 8);
  }
  __syncthreads();

  constexpr int KT = DM / 64;
  for (int kt = 0; kt < KT; ++kt) {
    const int buf = kt & 1;
#pragma unroll
    for (int ks = 0; ks < 4; ++ks) {
      bf16x8 af = *(const bf16x8*)&As[buf][mh * 32 + ln][ks * 16 + g * 8];
      bf16x8 wf = *(const bf16x8*)&Bs[buf][nh * 32 + ln][ks * 16 + g * 8];
      acc = __builtin_amdgcn_mfma_f32_32x32x16_bf16(af, wf, acc, 0, 0, 0);
    }
    if (kt + 1 < KT) {
      const int nb = buf ^ 1;
      *(bf16x8*)&As[nb][ar][ac]     = a0;
      *(bf16x8*)&As[nb][ar][ac + 8] = a1;
      *(bf16x8*)&Bs[nb][ar][ac]     = b0;
      *(bf16x8*)&Bs[nb][ar][ac + 8] = b1;
      if (kt + 2 < KT) {
        const __bf16* ap = Ap + (size_t)ar * DM + (kt + 2) * 64 + ac;
        a0 = *(const bf16x8*)ap; a1 = *(const bf16x8*)(ap + 8);
        const __bf16* wp = Wp + (size_t)ar * DM + (kt + 2) * 64 + ac;
        b0 = *(const bf16x8*)wp; b1 = *(const bf16x8*)(wp + 8);
      }
    }
    __syncthreads();
  }
  const float bv = bias[bn * 64 + nh * 32 + ln];
#pragma unroll
  for (int r = 0; r < 16; ++r) {
    int row = bm * 64 + mh * 32 + (r & 3) + 8 * (r >> 2) + 4 * g;
    out[(size_t)row * DM + bn * 64 + nh * 32 + ln] = acc[r] + bv;
  }
}

// ---------------------------------------------------------------- launch
extern "C" void kernel_launch(void* const* d_in, const int* in_sizes, int n_in,
                              void* d_out, int out_size, void* d_ws, size_t ws_size,
                              hipStream_t stream) {
  const float* Q = (const float*)d_in[0];
  const float* K = (const float*)d_in[1];
  const float* V = (const float*)d_in[2];
  const float* W = (const float*)d_in[3];
  const float* b = (const float*)d_in[4];
  float* out = (float*)d_out;

  __bf16* ws  = (__bf16*)d_ws;
  __bf16* Qb  = ws;
  __bf16* Kb  = Qb + QKV_ELEMS;
  __bf16* Vtg = Kb + QKV_ELEMS;               // (b,h,d,kv) bf16
  __bf16* Cc  = Vtg + QKV_ELEMS;              // concat (B,S,H,D) bf16
  __bf16* Wt  = Cc + QKV_ELEMS;               // (n,k) bf16

  convert_qk<<<dim3((unsigned)(QKV_ELEMS / (256 * 8)), 2, 1), 256, 0, stream>>>(Q, K, Qb, Kb);
  convert_vt<<<dim3(Sn / 64, Bn * Hn, 1), 256, 0, stream>>>(V, Vtg);
  convert_w<<<dim3(DM / 64, DM / 64, 1), 256, 0, stream>>>(W, Wt);
  attn<<<dim3(Sn / 128, Hn, Bn), 512, 0, stream>>>(Qb, Kb, Vtg, Cc);
  proj<<<dim3(Bn * Sn / 64, DM / 64, 1), 256, 0, stream>>>(Cc, Wt, b, out);
}

// Round 6
// 159.246 us; speedup vs baseline: 1.0351x; 1.0351x over previous
//
#include <hip/hip_runtime.h>
#include <hip/hip_bf16.h>

// B=2, H=16, S=2048, D=64, DMODEL=1024
// Round 6: q-ILP=2 attention (each wave owns 64 q rows) with NO P exchange:
// the PV reduction order over kv is permuted so the B-fragment is exactly the
// C/D registers each lane already holds (kv_local = s*16 + g*4 + 8*(j>>2) +
// (j&3)); V^T compensates by reading its k-slice as two b64 runs. Round 5's
// permlane bug is gone (no cross-lane op at all). Converts fused (1 kernel),
// proj = round-3 128x64 dbuf shape.

typedef float  f32x16 __attribute__((ext_vector_type(16)));
typedef float  f32x4v __attribute__((ext_vector_type(4)));
typedef float  f32x2v __attribute__((ext_vector_type(2)));
typedef __bf16 bf16x8 __attribute__((ext_vector_type(8)));
typedef __bf16 bf16x4 __attribute__((ext_vector_type(4)));
typedef __bf16 bf16x2 __attribute__((ext_vector_type(2)));

static constexpr int Bn = 2, Hn = 16, Sn = 2048, Dn = 64, DM = 1024;
static constexpr size_t QKV_ELEMS = (size_t)Bn * Hn * Sn * Dn;   // 4,194,304

#define QSCALE 0.18033688011112042f   // 0.125 * log2(e)

#if __has_builtin(__builtin_amdgcn_cvt_pk_bf16_f32)
static __device__ __forceinline__ unsigned pack2(float a, float b) {
  bf16x2 t = __builtin_amdgcn_cvt_pk_bf16_f32(a, b);
  union { bf16x2 v; unsigned u; } c; c.v = t; return c.u;
}
#else
static __device__ __forceinline__ unsigned pack2(float a, float b) {
  union { __bf16 h; unsigned short s; } ua, ub;
  ua.h = (__bf16)a; ub.h = (__bf16)b;
  return (unsigned)ua.s | ((unsigned)ub.s << 16);
}
#endif

static __device__ __forceinline__ void unzip8(const unsigned* wds, bf16x8* r0, bf16x8* r1) {
  union { unsigned u[4]; bf16x8 v; } a, b;
#pragma unroll
  for (int i = 0; i < 4; ++i) {
    unsigned lo = wds[2 * i], hi = wds[2 * i + 1];
    a.u[i] = (lo & 0xffffu) | (hi << 16);
    b.u[i] = (lo >> 16) | (hi & 0xffff0000u);
  }
  *r0 = a.v; *r1 = b.v;
}

// ------------------------------------------------- fused converts (1 kernel)
// blocks [0,2048): Q scale-convert; [2048,4096): K convert;
// [4096,5120): V transpose (b,h,kv,d)->(b,h,d,kv); [5120,5376): W transpose.
__global__ __launch_bounds__(256) void convert_all(
    const float* __restrict__ q, const float* __restrict__ k,
    const float* __restrict__ v, const float* __restrict__ w,
    __bf16* __restrict__ qo, __bf16* __restrict__ ko,
    __bf16* __restrict__ vt, __bf16* __restrict__ wt) {
  __shared__ __bf16 T[64][74];
  const int bid = blockIdx.x, t = threadIdx.x;

  if (bid < 4096) {
    const int z = bid >> 11;          // 0: Q, 1: K
    const int bx = bid & 2047;
    const float* src = z ? k : q;
    __bf16* dst      = z ? ko : qo;
    const float scale = z ? 1.0f : QSCALE;
    size_t i = ((size_t)bx * 256 + t) * 8;
    f32x4v a = *(const f32x4v*)(src + i);
    f32x4v b = *(const f32x4v*)(src + i + 4);
    bf16x8 o;
#pragma unroll
    for (int j = 0; j < 4; ++j) { o[j] = (__bf16)(a[j] * scale); o[4 + j] = (__bf16)(b[j] * scale); }
    *(bf16x8*)(dst + i) = o;
    return;
  }

  // transpose tasks: load 64x64 fp32 tile -> bf16 LDS (stride 74) -> emit ^T
  const float* s0;
  __bf16* dst0;
  size_t dst_stride;
  {
    const int r = t >> 2, c0 = (t & 3) * 16;
    if (bid < 5120) {
      const int idx = bid - 4096;
      const int kv0 = (idx & 31) * 64, bh = idx >> 5;
      s0 = v + ((size_t)bh * Sn + kv0 + r) * Dn + c0;
      dst0 = vt + (size_t)bh * Dn * Sn + kv0;
      dst_stride = Sn;
    } else {
      const int idx = bid - 5120;
      const int nt = (idx & 15) * 64, kt = (idx >> 4) * 64;
      s0 = w + (size_t)(kt + r) * DM + nt + c0;
      dst0 = wt + (size_t)nt * DM + kt;
      dst_stride = DM;
    }
    union { bf16x8 v8; unsigned u[4]; } o0, o1;
#pragma unroll
    for (int i = 0; i < 2; ++i) {
      f32x4v f = *(const f32x4v*)(s0 + i * 4);
#pragma unroll
      for (int j = 0; j < 4; ++j) o0.v8[i * 4 + j] = (__bf16)f[j];
    }
#pragma unroll
    for (int i = 0; i < 2; ++i) {
      f32x4v f = *(const f32x4v*)(s0 + 8 + i * 4);
#pragma unroll
      for (int j = 0; j < 4; ++j) o1.v8[i * 4 + j] = (__bf16)f[j];
    }
#pragma unroll
    for (int j = 0; j < 4; ++j) {
      *(unsigned*)&T[r][c0 + 2 * j]     = o0.u[j];
      *(unsigned*)&T[r][c0 + 8 + 2 * j] = o1.u[j];
    }
  }
  __syncthreads();
  const int rp = t >> 3, k0 = (t & 7) * 8;  // out rows 2rp,2rp+1; chunk k0
  unsigned wds[8];
#pragma unroll
  for (int i = 0; i < 8; ++i) wds[i] = *(const unsigned*)&T[k0 + i][2 * rp];
  bf16x8 r0, r1; unzip8(wds, &r0, &r1);
  __bf16* d0 = dst0 + (size_t)(2 * rp) * dst_stride + k0;
  *(bf16x8*)d0 = r0;
  *(bf16x8*)(d0 + dst_stride) = r1;
}

// ---------------------------------------------------------------- attention
// grid (S/128, H, B), 256 threads = 4 waves = (qg in {0,1} x 64 q-rows,
// kh in {0,1} x 32-kv half). q-ILP=2: 4 kf b128 + 8 vf b64 reads feed 16 MFMA.
// PV kv-order permuted to match the C/D register layout -> P^T B-frag is the
// lane's own packed words, no cross-lane exchange.
__global__ __launch_bounds__(256, 3) void attn(
    const __bf16* __restrict__ Qb, const __bf16* __restrict__ Kb,
    const __bf16* __restrict__ Vtg, __bf16* __restrict__ Cc) {
  const int tid = threadIdx.x;
  const int wave = tid >> 6, lane = tid & 63;
  const int ln = lane & 31, g = lane >> 5;
  const int qg = wave >> 1, kh = wave & 1;
  const int qb = blockIdx.x, h = blockIdx.y, bz = blockIdx.z;

  __shared__ __bf16 smem[2][2][64][72];      // 36864 B
  __bf16 (*Ks)[64][72] = smem[0];            // [buf][kv][d]
  __bf16 (*Vs)[64][72] = smem[1];            // [buf][d][kv]

  const size_t hoff = (size_t)(bz * Hn + h) * Sn * Dn;
  const __bf16* Qp = Qb + hoff + (size_t)(qb * 128 + qg * 64) * Dn;
  const __bf16* Kp = Kb + hoff;      // [kv][d]
  const __bf16* Vp = Vtg + hoff;     // [d][kv]

  bf16x8 qf[2][4];
#pragma unroll
  for (int qt = 0; qt < 2; ++qt)
#pragma unroll
    for (int ks = 0; ks < 4; ++ks)
      qf[qt][ks] = *(const bf16x8*)(Qp + (size_t)(qt * 32 + ln) * Dn + ks * 16 + g * 8);

  const int sr = tid >> 2, sc = (tid & 3) * 16;
  const __bf16* kbase = Kp + (size_t)sr * Dn + sc;
  const __bf16* vbase = Vp + (size_t)sr * Sn + sc;

  bf16x8 k0r = *(const bf16x8*)kbase, k1r = *(const bf16x8*)(kbase + 8);
  bf16x8 v0r = *(const bf16x8*)vbase, v1r = *(const bf16x8*)(vbase + 8);
  *(bf16x8*)&Ks[0][sr][sc]     = k0r;
  *(bf16x8*)&Ks[0][sr][sc + 8] = k1r;
  *(bf16x8*)&Vs[0][sr][sc]     = v0r;
  *(bf16x8*)&Vs[0][sr][sc + 8] = v1r;
  k0r = *(const bf16x8*)(kbase + (size_t)64 * Dn);
  k1r = *(const bf16x8*)(kbase + (size_t)64 * Dn + 8);
  v0r = *(const bf16x8*)(vbase + 64);
  v1r = *(const bf16x8*)(vbase + 64 + 8);
  __syncthreads();

  f32x16 O[2][2] = {{{}, {}}, {{}, {}}};     // [qt][d-half]
  float Lown[2] = {0.0f, 0.0f};
  constexpr int NT = Sn / 64;

  for (int kt = 0; kt < NT; ++kt) {
    const int buf = kt & 1;

    // shared K-fragments for both q-tiles (4 ds_read_b128)
    bf16x8 kf[4];
#pragma unroll
    for (int ks = 0; ks < 4; ++ks)
      kf[ks] = *(const bf16x8*)&Ks[buf][kh * 32 + ln][ks * 16 + g * 8];

    unsigned w[2][8];
#pragma unroll
    for (int qt = 0; qt < 2; ++qt) {
      f32x16 s = {};
#pragma unroll
      for (int ks = 0; ks < 4; ++ks)
        s = __builtin_amdgcn_mfma_f32_32x32x16_bf16(kf[ks], qf[qt][ks], s, 0, 0, 0);
      float p[16];
#pragma unroll
      for (int r = 0; r < 16; ++r) p[r] = __builtin_amdgcn_exp2f(s[r]);
      f32x2v s2 = {0.0f, 0.0f};
#pragma unroll
      for (int tt = 0; tt < 8; ++tt) { f32x2v t2 = {p[2 * tt], p[2 * tt + 1]}; s2 += t2; }
      Lown[qt] += s2[0] + s2[1];
#pragma unroll
      for (int tt = 0; tt < 8; ++tt) w[qt][tt] = pack2(p[2 * tt], p[2 * tt + 1]);
    }

    // stage next tile; prefetch kt+2
    if (kt + 1 < NT) {
      const int nb = buf ^ 1;
      *(bf16x8*)&Ks[nb][sr][sc]     = k0r;
      *(bf16x8*)&Ks[nb][sr][sc + 8] = k1r;
      *(bf16x8*)&Vs[nb][sr][sc]     = v0r;
      *(bf16x8*)&Vs[nb][sr][sc + 8] = v1r;
      if (kt + 2 < NT) {
        const __bf16* kp = kbase + (size_t)(kt + 2) * 64 * Dn;
        k0r = *(const bf16x8*)kp; k1r = *(const bf16x8*)(kp + 8);
        const __bf16* vp = vbase + (kt + 2) * 64;
        v0r = *(const bf16x8*)vp; v1r = *(const bf16x8*)(vp + 8);
      }
    }

    // PV with permuted kv order: step s4 covers C/D regs [8*s4, 8*s4+8).
    // B-frag k = g*8+j  <->  kv_local = kh*32 + s4*16 + g*4 + 8*(j>>2) + (j&3)
    // so the B words are w[s4*4..s4*4+3] verbatim, and V^T supplies k as two
    // b64 runs at columns (kh*32 + s4*16 + g*4) and (+8).
#pragma unroll
    for (int s4 = 0; s4 < 2; ++s4) {
      const int cb = kh * 32 + s4 * 16 + g * 4;
      union { bf16x4 h[2]; bf16x8 v; } vf0, vf1;
      vf0.h[0] = *(const bf16x4*)&Vs[buf][ln][cb];
      vf0.h[1] = *(const bf16x4*)&Vs[buf][ln][cb + 8];
      vf1.h[0] = *(const bf16x4*)&Vs[buf][32 + ln][cb];
      vf1.h[1] = *(const bf16x4*)&Vs[buf][32 + ln][cb + 8];
#pragma unroll
      for (int qt = 0; qt < 2; ++qt) {
        union { unsigned u[4]; bf16x8 v; } pu;
        pu.u[0] = w[qt][s4 * 4 + 0];
        pu.u[1] = w[qt][s4 * 4 + 1];
        pu.u[2] = w[qt][s4 * 4 + 2];
        pu.u[3] = w[qt][s4 * 4 + 3];
        O[qt][0] = __builtin_amdgcn_mfma_f32_32x32x16_bf16(vf0.v, pu.v, O[qt][0], 0, 0, 0);
        O[qt][1] = __builtin_amdgcn_mfma_f32_32x32x16_bf16(vf1.v, pu.v, O[qt][1], 0, 0, 0);
      }
    }
    __syncthreads();
  }

  // ---- kh pair-reduction via LDS; normalize; transpose; coalesced store ----
  float Lred[2];
#pragma unroll
  for (int qt = 0; qt < 2; ++qt) Lred[qt] = Lown[qt] + __shfl_xor(Lown[qt], 32);

  float* Ex = (float*)smem;                  // [2*64][68] f32 = 34816 B
  const int slot = (qg * 64 + lane) * 68;
  if (kh == 1) {
#pragma unroll
    for (int qt = 0; qt < 2; ++qt)
#pragma unroll
      for (int dh = 0; dh < 2; ++dh)
#pragma unroll
        for (int i = 0; i < 4; ++i) {
          f32x4v t = {O[qt][dh][4 * i], O[qt][dh][4 * i + 1],
                      O[qt][dh][4 * i + 2], O[qt][dh][4 * i + 3]};
          *(f32x4v*)&Ex[slot + qt * 32 + dh * 16 + 4 * i] = t;
        }
    Ex[slot + 64] = Lred[0];
    Ex[slot + 65] = Lred[1];
  }
  __syncthreads();
  float inv[2] = {0.0f, 0.0f};
  if (kh == 0) {
#pragma unroll
    for (int qt = 0; qt < 2; ++qt)
#pragma unroll
      for (int dh = 0; dh < 2; ++dh)
#pragma unroll
        for (int i = 0; i < 4; ++i) {
          f32x4v t = *(const f32x4v*)&Ex[slot + qt * 32 + dh * 16 + 4 * i];
#pragma unroll
          for (int c = 0; c < 4; ++c) O[qt][dh][4 * i + c] += t[c];
        }
    inv[0] = 1.0f / (Lred[0] + Ex[slot + 64]);
    inv[1] = 1.0f / (Lred[1] + Ex[slot + 65]);
  }
  __syncthreads();
  __bf16* T = (__bf16*)smem;                 // [128][72] bf16 = 18432 B
  if (kh == 0) {
#pragma unroll
    for (int qt = 0; qt < 2; ++qt)
#pragma unroll
      for (int dh = 0; dh < 2; ++dh)
#pragma unroll
        for (int a = 0; a < 4; ++a) {
          bf16x4 t4;
#pragma unroll
          for (int c = 0; c < 4; ++c) t4[c] = (__bf16)(O[qt][dh][4 * a + c] * inv[qt]);
          *(bf16x4*)&T[(qg * 64 + qt * 32 + ln) * 72 + dh * 32 + 8 * a + 4 * g] = t4;
        }
  }
  __syncthreads();
  const int q0 = qb * 128;
#pragma unroll
  for (int i = 0; i < 4; ++i) {
    const int rq = i * 32 + (tid >> 3);
    const int c8 = (tid & 7) * 8;
    bf16x8 o = *(const bf16x8*)&T[rq * 72 + c8];
    size_t base = (((size_t)bz * Sn + q0 + rq) * Hn + h) * Dn + c8;
    *(bf16x8*)&Cc[base] = o;
  }
}

// ---------------------------------------------------------------- projection
// out(4096,1024) = concat @ W + b. 128x64 tile, dbuf, one barrier per K-iter.
__global__ __launch_bounds__(256, 2) void proj(
    const __bf16* __restrict__ A, const __bf16* __restrict__ Wt,
    const float* __restrict__ bias, float* __restrict__ out) {
  const int tid = threadIdx.x, wave = tid >> 6, lane = tid & 63;
  const int ln = lane & 31, g = lane >> 5;
  const int bm = blockIdx.x, bn = blockIdx.y;
  __shared__ __bf16 As[2][128][72];
  __shared__ __bf16 Bs[2][64][72];
  const int ar = tid >> 1, ac = (tid & 1) * 32;
  const int br = tid >> 2, bc = (tid & 3) * 16;
  f32x16 acc0 = {}, acc1 = {};
  const __bf16* Ap = A + (size_t)(bm * 128) * DM;
  const __bf16* Wp = Wt + (size_t)(bn * 64) * DM;

  bf16x8 a0, a1, a2, a3, b0, b1;
  {
    const __bf16* ap = Ap + (size_t)ar * DM + ac;
    a0 = *(const bf16x8*)ap;        a1 = *(const bf16x8*)(ap + 8);
    a2 = *(const bf16x8*)(ap + 16); a3 = *(const bf16x8*)(ap + 24);
    const __bf16* wp = Wp + (size_t)br * DM + bc;
    b0 = *(const bf16x8*)wp; b1 = *(const bf16x8*)(wp + 8);
  }
  *(bf16x8*)&As[0][ar][ac]      = a0;
  *(bf16x8*)&As[0][ar][ac + 8]  = a1;
  *(bf16x8*)&As[0][ar][ac + 16] = a2;
  *(bf16x8*)&As[0][ar][ac + 24] = a3;
  *(bf16x8*)&Bs[0][br][bc]      = b0;
  *(bf16x8*)&Bs[0][br][bc + 8]  = b1;
  {
    const __bf16* ap = Ap + (size_t)ar * DM + 64 + ac;
    a0 = *(const bf16x8*)ap;        a1 = *(const bf16x8*)(ap + 8);
    a2 = *(const bf16x8*)(ap + 16); a3 = *(const bf16x8*)(ap + 24);
    const __bf16* wp = Wp + (size_t)br * DM + 64 + bc;
    b0 = *(const bf16x8*)wp; b1 = *(const bf16x8*)(wp + 8);
  }
  __syncthreads();

  constexpr int KT = DM / 64;
  for (int kt = 0; kt < KT; ++kt) {
    const int buf = kt & 1;
#pragma unroll
    for (int ks = 0; ks < 4; ++ks) {
      bf16x8 af  = *(const bf16x8*)&As[buf][wave * 32 + ln][ks * 16 + g * 8];
      bf16x8 wf0 = *(const bf16x8*)&Bs[buf][ln][ks * 16 + g * 8];
      bf16x8 wf1 = *(const bf16x8*)&Bs[buf][32 + ln][ks * 16 + g * 8];
      acc0 = __builtin_amdgcn_mfma_f32_32x32x16_bf16(af, wf0, acc0, 0, 0, 0);
      acc1 = __builtin_amdgcn_mfma_f32_32x32x16_bf16(af, wf1, acc1, 0, 0, 0);
    }
    if (kt + 1 < KT) {
      const int nb = buf ^ 1;
      *(bf16x8*)&As[nb][ar][ac]      = a0;
      *(bf16x8*)&As[nb][ar][ac + 8]  = a1;
      *(bf16x8*)&As[nb][ar][ac + 16] = a2;
      *(bf16x8*)&As[nb][ar][ac + 24] = a3;
      *(bf16x8*)&Bs[nb][br][bc]      = b0;
      *(bf16x8*)&Bs[nb][br][bc + 8]  = b1;
      if (kt + 2 < KT) {
        const __bf16* ap = Ap + (size_t)ar * DM + (kt + 2) * 64 + ac;
        a0 = *(const bf16x8*)ap;        a1 = *(const bf16x8*)(ap + 8);
        a2 = *(const bf16x8*)(ap + 16); a3 = *(const bf16x8*)(ap + 24);
        const __bf16* wp = Wp + (size_t)br * DM + (kt + 2) * 64 + bc;
        b0 = *(const bf16x8*)wp; b1 = *(const bf16x8*)(wp + 8);
      }
    }
    __syncthreads();
  }
  float bv0 = bias[bn * 64 + ln], bv1 = bias[bn * 64 + 32 + ln];
#pragma unroll
  for (int r = 0; r < 16; ++r) {
    int row = bm * 128 + wave * 32 + (r & 3) + ((r >> 2) << 3) + (g << 2);
    out[(size_t)row * DM + bn * 64 + ln]      = acc0[r] + bv0;
    out[(size_t)row * DM + bn * 64 + 32 + ln] = acc1[r] + bv1;
  }
}

// ---------------------------------------------------------------- launch
extern "C" void kernel_launch(void* const* d_in, const int* in_sizes, int n_in,
                              void* d_out, int out_size, void* d_ws, size_t ws_size,
                              hipStream_t stream) {
  const float* Q = (const float*)d_in[0];
  const float* K = (const float*)d_in[1];
  const float* V = (const float*)d_in[2];
  const float* W = (const float*)d_in[3];
  const float* b = (const float*)d_in[4];
  float* out = (float*)d_out;

  __bf16* ws  = (__bf16*)d_ws;
  __bf16* Qb  = ws;
  __bf16* Kb  = Qb + QKV_ELEMS;
  __bf16* Vtg = Kb + QKV_ELEMS;               // (b,h,d,kv) bf16
  __bf16* Cc  = Vtg + QKV_ELEMS;              // concat (B,S,H,D) bf16
  __bf16* Wt  = Cc + QKV_ELEMS;               // (n,k) bf16

  convert_all<<<dim3(5376, 1, 1), 256, 0, stream>>>(Q, K, V, W, Qb, Kb, Vtg, Wt);
  attn<<<dim3(Sn / 128, Hn, Bn), 256, 0, stream>>>(Qb, Kb, Vtg, Cc);
  proj<<<dim3(Bn * Sn / 128, DM / 64, 1), 256, 0, stream>>>(Cc, Wt, b, out);
}